// Round 5
// baseline (592.629 us; speedup 1.0000x reference)
//
#include <hip/hip_runtime.h>
#include <hip/hip_bf16.h>

using bf16x8 = __attribute__((ext_vector_type(8))) short;
using f32x4  = __attribute__((ext_vector_type(4))) float;
typedef unsigned short u16;

__device__ __forceinline__ u16 f2bf(float f) {
  unsigned int u = __float_as_uint(f);
  u += 0x7FFFu + ((u >> 16) & 1u);
  return (u16)(u >> 16);
}

__device__ __forceinline__ float bf2f(u16 b) {
  return __uint_as_float(((unsigned int)b) << 16);
}

__device__ __forceinline__ f32x4 mfma16(bf16x8 a, bf16x8 b, f32x4 c) {
  return __builtin_amdgcn_mfma_f32_16x16x32_bf16(a, b, c, 0, 0, 0);
}

// tanh(p) for p in [0,1] (softmax probs; here p <= ~0.06).
// Odd Taylor to p^9: error <1e-7 for p<=0.3, <7e-3 even at p=1.
__device__ __forceinline__ float tanh_poly(float p) {
  float x2 = p * p;
  float r = fmaf(x2, 0.021869488f, -0.053968254f);   // 62/2835, -17/315
  r = fmaf(x2, r, 0.13333333f);                      // 2/15
  r = fmaf(x2, r, -0.33333333f);                     // -1/3
  r = fmaf(x2, r, 1.0f);
  return p * r;
}

#define GLL16(gp, lp) __builtin_amdgcn_global_load_lds( \
    (const __attribute__((address_space(1))) unsigned*)(gp), \
    (__attribute__((address_space(3))) unsigned*)(lp), 16, 0, 0)

// ---------------------------------------------------------------------------
// fp32 -> bf16 converts (memory-bound)
// ---------------------------------------------------------------------------
__global__ __launch_bounds__(256) void cvt_kernel(
    const float* __restrict__ src, u16* __restrict__ dst) {
  const int i = (blockIdx.x * 256 + threadIdx.x) * 8;
  float4 v0 = *reinterpret_cast<const float4*>(src + i);
  float4 v1 = *reinterpret_cast<const float4*>(src + i + 4);
  u16 o[8] = {f2bf(v0.x), f2bf(v0.y), f2bf(v0.z), f2bf(v0.w),
              f2bf(v1.x), f2bf(v1.y), f2bf(v1.z), f2bf(v1.w)};
  *reinterpret_cast<int4*>(dst + i) = *reinterpret_cast<int4*>(o);
}

__global__ __launch_bounds__(256) void cvtW_kernel(
    const float* __restrict__ w0, const float* __restrict__ w1,
    const float* __restrict__ w2, u16* __restrict__ dst) {
  const float* src = (blockIdx.y == 0) ? w0 : (blockIdx.y == 1) ? w1 : w2;
  u16* d = dst + (size_t)blockIdx.y * 1048576;
  const int i = (blockIdx.x * 256 + threadIdx.x) * 8;
  float4 v0 = *reinterpret_cast<const float4*>(src + i);
  float4 v1 = *reinterpret_cast<const float4*>(src + i + 4);
  u16 o[8] = {f2bf(v0.x), f2bf(v0.y), f2bf(v0.z), f2bf(v0.w),
              f2bf(v1.x), f2bf(v1.y), f2bf(v1.z), f2bf(v1.w)};
  *reinterpret_cast<int4*>(d + i) = *reinterpret_cast<int4*>(o);
}

// ---------------------------------------------------------------------------
// Projection GEMM (bf16 in/out): Y = (X @ W^T + bias) * scale.
// m97 structure: global_load_lds width-16 staging into LINEAR [128][32] LDS,
// double-buffered, one barrier per K-step, prefetch next tile before compute.
// mat 0: Q (normal layout), 1: K (normal), 2: V (transposed per head:
//        Y[(b*1024 + n)*1024 + s])
// ---------------------------------------------------------------------------
__global__ __launch_bounds__(256) void proj_kernel(
    const u16* __restrict__ X, const u16* __restrict__ W,
    const float* __restrict__ Bi, u16* __restrict__ Y, int mat, float scale)
{
  __shared__ u16 As[2][128][32];   // 8 KB per buffer, linear (gll requirement)
  __shared__ u16 Bs[2][128][32];

  const int tid  = threadIdx.x;
  const int lane = tid & 63;
  const int w    = tid >> 6;
  const int m0 = blockIdx.y * 128;
  const int n0 = blockIdx.x * 128;
  const int wm = (w >> 1) * 64;
  const int wn = (w & 1) * 64;
  const int fr = lane & 15;
  const int fg = lane >> 4;

  // staging: wave w covers rows [w*32, w*32+32); chunk c = 16 rows = 1024 B.
  // lane l -> row c*16 + (l>>2), col elems (l&3)*8;  LDS dest = base + l*16.
  const int srow = lane >> 2;
  const int scol = (lane & 3) * 8;
  const u16* agp = X + (size_t)(m0 + w*32 + srow) * 1024 + scol;
  const u16* bgp = W + (size_t)(n0 + w*32 + srow) * 1024 + scol;

  f32x4 zero = {0.f, 0.f, 0.f, 0.f};
  f32x4 acc[4][4];
#pragma unroll
  for (int i = 0; i < 4; i++)
#pragma unroll
    for (int j = 0; j < 4; j++) acc[i][j] = zero;

#define STAGE(buf, kk)                                            \
  do {                                                            \
    GLL16(agp + (kk),            &As[buf][w*32     ][0]);         \
    GLL16(agp + (kk) + 16*1024,  &As[buf][w*32 + 16][0]);         \
    GLL16(bgp + (kk),            &Bs[buf][w*32     ][0]);         \
    GLL16(bgp + (kk) + 16*1024,  &Bs[buf][w*32 + 16][0]);         \
  } while (0)

  STAGE(0, 0);
  __syncthreads();   // drains vmcnt (gll) + barrier

  int cur = 0;
  for (int kt = 0; kt < 32; kt++) {
    if (kt < 31) STAGE(cur ^ 1, (kt + 1) * 32);

    bf16x8 af[4], bff[4];
#pragma unroll
    for (int i = 0; i < 4; i++) {
      af[i]  = *reinterpret_cast<const bf16x8*>(&As[cur][wm + i*16 + fr][fg*8]);
      bff[i] = *reinterpret_cast<const bf16x8*>(&Bs[cur][wn + i*16 + fr][fg*8]);
    }
#pragma unroll
    for (int i = 0; i < 4; i++)
#pragma unroll
      for (int j = 0; j < 4; j++)
        acc[i][j] = mfma16(af[i], bff[j], acc[i][j]);

    __syncthreads();  // drains prefetch vmcnt + lgkm; flip buffers
    cur ^= 1;
  }
#undef STAGE

  // epilogue: C/D layout row=(lane>>4)*4+reg, col=lane&15
#pragma unroll
  for (int j = 0; j < 4; j++) {
    const int n = n0 + wn + j*16 + fr;
    const float bias = Bi[n];
#pragma unroll
    for (int i = 0; i < 4; i++) {
      const int mbase = m0 + wm + i*16 + fg*4;
      if (mat == 2) {
        u16 pk[4];
#pragma unroll
        for (int r = 0; r < 4; r++) pk[r] = f2bf((acc[i][j][r] + bias) * scale);
        const int bidx = mbase >> 10;
        const int s = mbase & 1023;
        *reinterpret_cast<uint2*>(&Y[((size_t)(bidx * 1024 + n)) * 1024 + s]) =
            *reinterpret_cast<uint2*>(pk);
      } else {
#pragma unroll
        for (int r = 0; r < 4; r++) {
          Y[(size_t)(mbase + r) * 1024 + n] = f2bf((acc[i][j][r] + bias) * scale);
        }
      }
    }
  }
}

// ---------------------------------------------------------------------------
// Attention output kernel. 2048 blocks, 256 threads (4 waves).
// XCD-locality decode: xcd = bid&7; all 16 q-tile blocks of a (b,h) share an
// XCD so its 256KB K/V slice stays L2-resident (R4-proven: FETCH 218->25MB).
// Structure: R3 (zero barriers, K/V frags direct from global/L2, tiny LDS ->
// high occupancy). Wave w handles q rows [qt*64 + w*16, +16).
// Pass 1: Z = sum_k exp(s-8).  Pass 2: t = tanh_poly(exp(s-8)*rz), O += t@V.
// ---------------------------------------------------------------------------
__global__ __launch_bounds__(256) void attn_out_kernel(
    const u16* __restrict__ Qbf, const u16* __restrict__ Kbf, const u16* __restrict__ Vt,
    float* __restrict__ outA, float* __restrict__ rcpZ)
{
  const int bid = blockIdx.x;
  const int xcd = bid & 7;
  const int wi  = bid >> 3;
  const int qt  = wi & 15;
  const int bh  = ((wi >> 4) << 3) | xcd;  // bijective; same (b,h) -> same XCD
  const int b   = bh >> 4;
  const int h   = bh & 15;

  const int tid  = threadIdx.x;
  const int lane = tid & 63;
  const int w    = tid >> 6;
  const int fr = lane & 15;
  const int fg = lane >> 4;

  __shared__ u16 Tl[4][16][40];  // per-wave t relayout buffer (5 KB)

  const int qbase = qt * 64 + w * 16;

  // Q fragments (Q pre-scaled by 1/8 at projection time)
  const u16* qp = Qbf + ((size_t)(b * 1024 + qbase + fr)) * 1024 + h * 64 + fg * 8;
  const bf16x8 qf0 = *reinterpret_cast<const bf16x8*>(qp);
  const bf16x8 qf1 = *reinterpret_cast<const bf16x8*>(qp + 32);

  // K fragment base: row fr (+16 second frag), col h*64 + fg*8 (+32)
  const u16* kb = Kbf + ((size_t)(b * 1024 + fr)) * 1024 + h * 64 + fg * 8;
  // V fragment base (Vt is [B,H,64,S]): row e*16+fr, col kt*32 + fg*8
  const u16* vb = Vt + ((size_t)((b * 16 + h) * 64 + fr)) * 1024 + fg * 8;

  f32x4 zero = {0.f, 0.f, 0.f, 0.f};
  float zacc[4] = {0.f, 0.f, 0.f, 0.f};

  // ---------------- pass 1: Z ----------------
  for (int kt = 0; kt < 32; kt++) {
    const u16* kr = kb + (size_t)(kt * 32) * 1024;
    bf16x8 k0a = *reinterpret_cast<const bf16x8*>(kr);
    bf16x8 k0b = *reinterpret_cast<const bf16x8*>(kr + 32);
    bf16x8 k1a = *reinterpret_cast<const bf16x8*>(kr + 16 * 1024);
    bf16x8 k1b = *reinterpret_cast<const bf16x8*>(kr + 16 * 1024 + 32);
    f32x4 s0 = zero, s1 = zero;
    s0 = mfma16(qf0, k0a, s0); s0 = mfma16(qf1, k0b, s0);
    s1 = mfma16(qf0, k1a, s1); s1 = mfma16(qf1, k1b, s1);
#pragma unroll
    for (int r = 0; r < 4; r++)
      zacc[r] += __expf(s0[r] - 8.f) + __expf(s1[r] - 8.f);
  }
#pragma unroll
  for (int r = 0; r < 4; r++) {
    float z = zacc[r];
    z += __shfl_xor(z, 1); z += __shfl_xor(z, 2);
    z += __shfl_xor(z, 4); z += __shfl_xor(z, 8);
    zacc[r] = z;
  }
  float rz[4];
#pragma unroll
  for (int r = 0; r < 4; r++) rz[r] = 1.0f / zacc[r];
  if (fr == 0) {
#pragma unroll
    for (int r = 0; r < 4; r++)
      rcpZ[((size_t)(b * 16 + h)) * 1024 + qbase + fg * 4 + r] = rz[r];
  }

  // ---------------- pass 2: O = tanh(p) @ V ----------------
  f32x4 o[4];
#pragma unroll
  for (int e = 0; e < 4; e++) o[e] = zero;

  for (int kt = 0; kt < 32; kt++) {
    const u16* kr = kb + (size_t)(kt * 32) * 1024;
    bf16x8 k0a = *reinterpret_cast<const bf16x8*>(kr);
    bf16x8 k0b = *reinterpret_cast<const bf16x8*>(kr + 32);
    bf16x8 k1a = *reinterpret_cast<const bf16x8*>(kr + 16 * 1024);
    bf16x8 k1b = *reinterpret_cast<const bf16x8*>(kr + 16 * 1024 + 32);
    bf16x8 bv[4];
#pragma unroll
    for (int e = 0; e < 4; e++)
      bv[e] = *reinterpret_cast<const bf16x8*>(vb + (size_t)(e * 16) * 1024 + kt * 32);

    f32x4 s0 = zero, s1 = zero;
    s0 = mfma16(qf0, k0a, s0); s0 = mfma16(qf1, k0b, s0);
    s1 = mfma16(qf0, k1a, s1); s1 = mfma16(qf1, k1b, s1);

    // t = tanh_poly(p), stored into per-wave LDS tile in D-layout
#pragma unroll
    for (int r = 0; r < 4; r++) {
      float t0 = tanh_poly(__expf(s0[r] - 8.f) * rz[r]);
      float t1 = tanh_poly(__expf(s1[r] - 8.f) * rz[r]);
      Tl[w][fg*4 + r][fr]      = f2bf(t0);
      Tl[w][fg*4 + r][16 + fr] = f2bf(t1);
    }
    // re-read in A-fragment layout (same wave; lgkmcnt ordering by compiler)
    bf16x8 af = *reinterpret_cast<const bf16x8*>(&Tl[w][fr][fg*8]);
#pragma unroll
    for (int e = 0; e < 4; e++) o[e] = mfma16(af, bv[e], o[e]);
  }

#pragma unroll
  for (int e = 0; e < 4; e++)
#pragma unroll
    for (int r = 0; r < 4; r++)
      outA[((size_t)(b * 1024 + qbase + fg*4 + r)) * 1024 + h * 64 + e*16 + fr] = o[e][r];
}

// ---------------------------------------------------------------------------
// Weights kernel: outW[b,q,k] = mean_h tanh(exp(s-8)*rcpZ).
// grid (qt=32, ks=2, b=8) = 512 blocks, 512 threads (8 waves).
// Wave w owns output frag (qi=w>>2, ki=w&3); K fragments read DIRECTLY from
// global (no LDS staging, no barriers in the loop). h outer / kt inner with
// wsum[8] register accumulators -> 8 independent chains for latency hiding.
// ---------------------------------------------------------------------------
__global__ __launch_bounds__(512) void attn_w_kernel(
    const u16* __restrict__ Qbf, const u16* __restrict__ Kbf,
    const float* __restrict__ rcpZ, float* __restrict__ outW)
{
  const int qt = blockIdx.x;
  const int ks = blockIdx.y;
  const int b  = blockIdx.z;
  const int tid  = threadIdx.x;
  const int lane = tid & 63;
  const int w    = tid >> 6;
  const int qi = w >> 2;   // 0..1
  const int ki = w & 3;    // 0..3
  const int fr = lane & 15;
  const int fg = lane >> 4;

  __shared__ u16 Qall[32][1032];     // 2064 B stride
  __shared__ float statsL[16][32];   // [h][row]

  {
    const int qrow = tid >> 4;            // 0..31
    const int qoffb = (tid & 15) * 64;
    const u16* qsrc = Qbf + ((size_t)(b * 1024 + qt * 32 + qrow)) * 1024 + qoffb;
#pragma unroll
    for (int i = 0; i < 8; i++)
      *reinterpret_cast<int4*>(&Qall[qrow][qoffb + i*8]) =
          *reinterpret_cast<const int4*>(qsrc + i*8);
    const int hh = tid >> 5, rr = tid & 31;
    statsL[hh][rr] = rcpZ[((size_t)(b * 16 + hh)) * 1024 + qt * 32 + rr];
  }
  __syncthreads();

  const u16* kbase = Kbf + ((size_t)(b * 1024 + ks * 512 + ki * 16 + fr)) * 1024 + fg * 8;

  f32x4 wsum[8];
#pragma unroll
  for (int kt = 0; kt < 8; kt++) wsum[kt] = f32x4{0.f, 0.f, 0.f, 0.f};

  for (int h = 0; h < 16; h++) {
    bf16x8 a0 = *reinterpret_cast<const bf16x8*>(&Qall[qi*16 + fr][h*64 + fg*8]);
    bf16x8 a1 = *reinterpret_cast<const bf16x8*>(&Qall[qi*16 + fr][h*64 + 32 + fg*8]);
    float rza[4];
#pragma unroll
    for (int r = 0; r < 4; r++) rza[r] = statsL[h][qi*16 + fg*4 + r];

#pragma unroll 4
    for (int kt = 0; kt < 8; kt++) {
      bf16x8 b0 = *reinterpret_cast<const bf16x8*>(kbase + (size_t)kt * 65536 + h * 64);
      bf16x8 b1 = *reinterpret_cast<const bf16x8*>(kbase + (size_t)kt * 65536 + h * 64 + 32);
      f32x4 s = {0.f, 0.f, 0.f, 0.f};
      s = mfma16(a0, b0, s);
      s = mfma16(a1, b1, s);
#pragma unroll
      for (int r = 0; r < 4; r++)
        wsum[kt][r] += tanh_poly(__expf(s[r] - 8.f) * rza[r]);
    }
  }

#pragma unroll
  for (int kt = 0; kt < 8; kt++)
#pragma unroll
    for (int r = 0; r < 4; r++)
      outW[((size_t)(b*1024 + qt*32 + qi*16 + fg*4 + r)) * 1024 + ks*512 + kt*64 + ki*16 + fr] =
          wsum[kt][r] * 0.0625f;
}

// ---------------------------------------------------------------------------
extern "C" void kernel_launch(void* const* d_in, const int* in_sizes, int n_in,
                              void* d_out, int out_size, void* d_ws, size_t ws_size,
                              hipStream_t stream) {
  const float* query = (const float*)d_in[0];
  const float* key_  = (const float*)d_in[1];
  const float* value = (const float*)d_in[2];
  const float* Wq = (const float*)d_in[3];
  const float* bq = (const float*)d_in[4];
  const float* Wk = (const float*)d_in[5];
  const float* bk = (const float*)d_in[6];
  const float* Wv = (const float*)d_in[7];
  const float* bv = (const float*)d_in[8];

  float* outA = (float*)d_out;            // [8,1024,1024]
  float* outW = outA + 8388608;           // [8,1024,1024]

  u16* Qbf = (u16*)d_ws;                  // bf16, Q pre-scaled by 1/8
  u16* Kbf = Qbf + 8388608;
  u16* Vt  = Kbf + 8388608;               // [B,H,64,S] transposed per head
  u16* Xbf = Vt + 8388608;                // 16.8MB reusable input slot
  u16* Wbf = Xbf + 8388608;               // 3 x 1M bf16 weights
  float* rcpZ = (float*)(Wbf + 3145728);  // [B,H,S]

  cvtW_kernel<<<dim3(512, 3), 256, 0, stream>>>(Wq, Wk, Wv, Wbf);

  cvt_kernel<<<4096, 256, 0, stream>>>(query, Xbf);
  proj_kernel<<<dim3(8, 64), 256, 0, stream>>>(Xbf, Wbf, bq, Qbf, 0, 0.125f);

  cvt_kernel<<<4096, 256, 0, stream>>>(key_, Xbf);
  proj_kernel<<<dim3(8, 64), 256, 0, stream>>>(Xbf, Wbf + 1048576, bk, Kbf, 1, 1.0f);

  cvt_kernel<<<4096, 256, 0, stream>>>(value, Xbf);
  proj_kernel<<<dim3(8, 64), 256, 0, stream>>>(Xbf, Wbf + 2097152, bv, Vt, 2, 1.0f);

  attn_out_kernel<<<dim3(2048), dim3(256), 0, stream>>>(Qbf, Kbf, Vt, outA, rcpZ);
  attn_w_kernel<<<dim3(32, 2, 8), 512, 0, stream>>>(Qbf, Kbf, rcpZ, outW);
}

// Round 6
// 361.915 us; speedup vs baseline: 1.6375x; 1.6375x over previous
//
#include <hip/hip_runtime.h>
#include <hip/hip_bf16.h>

using bf16x8 = __attribute__((ext_vector_type(8))) short;
using f32x4  = __attribute__((ext_vector_type(4))) float;
typedef unsigned short u16;

__device__ __forceinline__ u16 f2bf(float f) {
  unsigned int u = __float_as_uint(f);
  u += 0x7FFFu + ((u >> 16) & 1u);
  return (u16)(u >> 16);
}

__device__ __forceinline__ float bf2f(u16 b) {
  return __uint_as_float(((unsigned int)b) << 16);
}

__device__ __forceinline__ f32x4 mfma16(bf16x8 a, bf16x8 b, f32x4 c) {
  return __builtin_amdgcn_mfma_f32_16x16x32_bf16(a, b, c, 0, 0, 0);
}

// tanh(p) for p in [0,1] (softmax probs; here p <= ~0.06).
// Odd Taylor to p^9: error <1e-7 for p<=0.3, <7e-3 even at p=1.
__device__ __forceinline__ float tanh_poly(float p) {
  float x2 = p * p;
  float r = fmaf(x2, 0.021869488f, -0.053968254f);   // 62/2835, -17/315
  r = fmaf(x2, r, 0.13333333f);                      // 2/15
  r = fmaf(x2, r, -0.33333333f);                     // -1/3
  r = fmaf(x2, r, 1.0f);
  return p * r;
}

#define GLL16(gp, lp) __builtin_amdgcn_global_load_lds( \
    (const __attribute__((address_space(1))) unsigned*)(gp), \
    (__attribute__((address_space(3))) unsigned*)(lp), 16, 0, 0)

// ---------------------------------------------------------------------------
// fp32 -> bf16 converts (memory-bound)
// ---------------------------------------------------------------------------
__global__ __launch_bounds__(256) void cvt_kernel(
    const float* __restrict__ src, u16* __restrict__ dst) {
  const int i = (blockIdx.x * 256 + threadIdx.x) * 8;
  float4 v0 = *reinterpret_cast<const float4*>(src + i);
  float4 v1 = *reinterpret_cast<const float4*>(src + i + 4);
  u16 o[8] = {f2bf(v0.x), f2bf(v0.y), f2bf(v0.z), f2bf(v0.w),
              f2bf(v1.x), f2bf(v1.y), f2bf(v1.z), f2bf(v1.w)};
  *reinterpret_cast<int4*>(dst + i) = *reinterpret_cast<int4*>(o);
}

__global__ __launch_bounds__(256) void cvtW_kernel(
    const float* __restrict__ w0, const float* __restrict__ w1,
    const float* __restrict__ w2, u16* __restrict__ dst) {
  const float* src = (blockIdx.y == 0) ? w0 : (blockIdx.y == 1) ? w1 : w2;
  u16* d = dst + (size_t)blockIdx.y * 1048576;
  const int i = (blockIdx.x * 256 + threadIdx.x) * 8;
  float4 v0 = *reinterpret_cast<const float4*>(src + i);
  float4 v1 = *reinterpret_cast<const float4*>(src + i + 4);
  u16 o[8] = {f2bf(v0.x), f2bf(v0.y), f2bf(v0.z), f2bf(v0.w),
              f2bf(v1.x), f2bf(v1.y), f2bf(v1.z), f2bf(v1.w)};
  *reinterpret_cast<int4*>(d + i) = *reinterpret_cast<int4*>(o);
}

// ---------------------------------------------------------------------------
// Projection GEMM (bf16 in/out): Y = (X @ W^T + bias) * scale.
// m97 structure: global_load_lds width-16 staging into LINEAR [128][32] LDS,
// double-buffered, one barrier per K-step, prefetch next tile before compute.
// ---------------------------------------------------------------------------
__global__ __launch_bounds__(256) void proj_kernel(
    const u16* __restrict__ X, const u16* __restrict__ W,
    const float* __restrict__ Bi, u16* __restrict__ Y, int mat, float scale)
{
  __shared__ u16 As[2][128][32];   // 8 KB per buffer, linear (gll requirement)
  __shared__ u16 Bs[2][128][32];

  const int tid  = threadIdx.x;
  const int lane = tid & 63;
  const int w    = tid >> 6;
  const int m0 = blockIdx.y * 128;
  const int n0 = blockIdx.x * 128;
  const int wm = (w >> 1) * 64;
  const int wn = (w & 1) * 64;
  const int fr = lane & 15;
  const int fg = lane >> 4;

  const int srow = lane >> 2;
  const int scol = (lane & 3) * 8;
  const u16* agp = X + (size_t)(m0 + w*32 + srow) * 1024 + scol;
  const u16* bgp = W + (size_t)(n0 + w*32 + srow) * 1024 + scol;

  f32x4 zero = {0.f, 0.f, 0.f, 0.f};
  f32x4 acc[4][4];
#pragma unroll
  for (int i = 0; i < 4; i++)
#pragma unroll
    for (int j = 0; j < 4; j++) acc[i][j] = zero;

#define STAGE(buf, kk)                                            \
  do {                                                            \
    GLL16(agp + (kk),            &As[buf][w*32     ][0]);         \
    GLL16(agp + (kk) + 16*1024,  &As[buf][w*32 + 16][0]);         \
    GLL16(bgp + (kk),            &Bs[buf][w*32     ][0]);         \
    GLL16(bgp + (kk) + 16*1024,  &Bs[buf][w*32 + 16][0]);         \
  } while (0)

  STAGE(0, 0);
  __syncthreads();   // drains vmcnt (gll) + barrier

  int cur = 0;
  for (int kt = 0; kt < 32; kt++) {
    if (kt < 31) STAGE(cur ^ 1, (kt + 1) * 32);

    bf16x8 af[4], bff[4];
#pragma unroll
    for (int i = 0; i < 4; i++) {
      af[i]  = *reinterpret_cast<const bf16x8*>(&As[cur][wm + i*16 + fr][fg*8]);
      bff[i] = *reinterpret_cast<const bf16x8*>(&Bs[cur][wn + i*16 + fr][fg*8]);
    }
#pragma unroll
    for (int i = 0; i < 4; i++)
#pragma unroll
      for (int j = 0; j < 4; j++)
        acc[i][j] = mfma16(af[i], bff[j], acc[i][j]);

    __syncthreads();  // drains prefetch vmcnt + lgkm; flip buffers
    cur ^= 1;
  }
#undef STAGE

  // epilogue: C/D layout row=(lane>>4)*4+reg, col=lane&15
#pragma unroll
  for (int j = 0; j < 4; j++) {
    const int n = n0 + wn + j*16 + fr;
    const float bias = Bi[n];
#pragma unroll
    for (int i = 0; i < 4; i++) {
      const int mbase = m0 + wm + i*16 + fg*4;
      if (mat == 2) {
        u16 pk[4];
#pragma unroll
        for (int r = 0; r < 4; r++) pk[r] = f2bf((acc[i][j][r] + bias) * scale);
        const int bidx = mbase >> 10;
        const int s = mbase & 1023;
        *reinterpret_cast<uint2*>(&Y[((size_t)(bidx * 1024 + n)) * 1024 + s]) =
            *reinterpret_cast<uint2*>(pk);
      } else {
#pragma unroll
        for (int r = 0; r < 4; r++) {
          Y[(size_t)(mbase + r) * 1024 + n] = f2bf((acc[i][j][r] + bias) * scale);
        }
      }
    }
  }
}

// ---------------------------------------------------------------------------
// Attention output kernel. 2048 blocks, 256 threads (4 waves).
// XCD-locality decode (R4-proven: FETCH 218->25MB): all 16 q-tile blocks of
// a (b,h) share an XCD so its 256KB K/V slice stays L2-resident.
// LDS-staged K/V (R2-proven ~117us structure) + T14 async-split double
// buffering: ONE barrier per kt; next tile's global load issues before the
// compute so L2 latency hides under MFMA+exp.
// Wave w handles q rows [qt*64 + w*16, +16).
// Pass 1: Z = sum_k exp(s-8).  Pass 2: t = tanh_poly(exp(s-8)*rz), O += t@V.
// ---------------------------------------------------------------------------
__global__ __launch_bounds__(256) void attn_out_kernel(
    const u16* __restrict__ Qbf, const u16* __restrict__ Kbf, const u16* __restrict__ Vt,
    float* __restrict__ outA, float* __restrict__ rcpZ)
{
  const int bid = blockIdx.x;
  const int xcd = bid & 7;
  const int wi  = bid >> 3;
  const int qt  = wi & 15;
  const int bh  = ((wi >> 4) << 3) | xcd;  // bijective; same (b,h) -> same XCD
  const int b   = bh >> 4;
  const int h   = bh & 15;

  const int tid  = threadIdx.x;
  const int lane = tid & 63;
  const int w    = tid >> 6;
  const int fr = lane & 15;
  const int fg = lane >> 4;

  __shared__ u16 Ks[2][32][88];   // 11264 B, 176B stride (2-way bank max)
  __shared__ u16 Vts[2][64][40];  // 10240 B, [e][k] (V pre-transposed in ws)
  __shared__ u16 Tl[4][16][40];   // 5120 B per-wave t relayout buffer

  const int qbase = qt * 64 + w * 16;

  // Q fragments (Q pre-scaled by 1/8 at projection time)
  const u16* qp = Qbf + ((size_t)(b * 1024 + qbase + fr)) * 1024 + h * 64 + fg * 8;
  const bf16x8 qf0 = *reinterpret_cast<const bf16x8*>(qp);
  const bf16x8 qf1 = *reinterpret_cast<const bf16x8*>(qp + 32);

  const int krow = tid >> 3;            // 0..31
  const int koff = (tid & 7) * 8;       // 0..56
  const u16* kp = Kbf + ((size_t)(b * 1024 + krow)) * 1024 + h * 64 + koff;

  const int vrow = tid >> 2;            // 0..63 (e)
  const int voff = (tid & 3) * 8;       // 0..24 (k within tile)
  const u16* vp = Vt + ((size_t)((b * 16 + h) * 64 + vrow)) * 1024 + voff;

  f32x4 zero = {0.f, 0.f, 0.f, 0.f};
  float zacc[4] = {0.f, 0.f, 0.f, 0.f};

  // ---------------- pass 1: Z ----------------
  {
    int4 kv = *reinterpret_cast<const int4*>(kp);
    *reinterpret_cast<int4*>(&Ks[0][krow][koff]) = kv;
  }
  __syncthreads();
  int cur = 0;
  for (int kt = 0; kt < 32; kt++) {
    int4 kvn;
    if (kt < 31) kvn = *reinterpret_cast<const int4*>(kp + (size_t)(kt + 1) * 32 * 1024);

    bf16x8 k0a = *reinterpret_cast<const bf16x8*>(&Ks[cur][fr][fg*8]);
    bf16x8 k0b = *reinterpret_cast<const bf16x8*>(&Ks[cur][fr][32 + fg*8]);
    bf16x8 k1a = *reinterpret_cast<const bf16x8*>(&Ks[cur][16 + fr][fg*8]);
    bf16x8 k1b = *reinterpret_cast<const bf16x8*>(&Ks[cur][16 + fr][32 + fg*8]);
    f32x4 s0 = zero, s1 = zero;
    s0 = mfma16(qf0, k0a, s0); s0 = mfma16(qf1, k0b, s0);
    s1 = mfma16(qf0, k1a, s1); s1 = mfma16(qf1, k1b, s1);
#pragma unroll
    for (int r = 0; r < 4; r++)
      zacc[r] += __expf(s0[r] - 8.f) + __expf(s1[r] - 8.f);

    if (kt < 31) *reinterpret_cast<int4*>(&Ks[cur ^ 1][krow][koff]) = kvn;
    __syncthreads();
    cur ^= 1;
  }
#pragma unroll
  for (int r = 0; r < 4; r++) {
    float z = zacc[r];
    z += __shfl_xor(z, 1); z += __shfl_xor(z, 2);
    z += __shfl_xor(z, 4); z += __shfl_xor(z, 8);
    zacc[r] = z;
  }
  float rz[4];
#pragma unroll
  for (int r = 0; r < 4; r++) rz[r] = 1.0f / zacc[r];
  if (fr == 0) {
#pragma unroll
    for (int r = 0; r < 4; r++)
      rcpZ[((size_t)(b * 16 + h)) * 1024 + qbase + fg * 4 + r] = rz[r];
  }

  // ---------------- pass 2: O = tanh(p) @ V ----------------
  f32x4 o[4];
#pragma unroll
  for (int e = 0; e < 4; e++) o[e] = zero;

  {
    int4 kv = *reinterpret_cast<const int4*>(kp);
    int4 vv = *reinterpret_cast<const int4*>(vp);
    *reinterpret_cast<int4*>(&Ks[0][krow][koff]) = kv;
    *reinterpret_cast<int4*>(&Vts[0][vrow][voff]) = vv;
  }
  __syncthreads();
  cur = 0;
  for (int kt = 0; kt < 32; kt++) {
    int4 kvn, vvn;
    if (kt < 31) {
      kvn = *reinterpret_cast<const int4*>(kp + (size_t)(kt + 1) * 32 * 1024);
      vvn = *reinterpret_cast<const int4*>(vp + (kt + 1) * 32);
    }

    bf16x8 k0a = *reinterpret_cast<const bf16x8*>(&Ks[cur][fr][fg*8]);
    bf16x8 k0b = *reinterpret_cast<const bf16x8*>(&Ks[cur][fr][32 + fg*8]);
    bf16x8 k1a = *reinterpret_cast<const bf16x8*>(&Ks[cur][16 + fr][fg*8]);
    bf16x8 k1b = *reinterpret_cast<const bf16x8*>(&Ks[cur][16 + fr][32 + fg*8]);
    f32x4 s0 = zero, s1 = zero;
    s0 = mfma16(qf0, k0a, s0); s0 = mfma16(qf1, k0b, s0);
    s1 = mfma16(qf0, k1a, s1); s1 = mfma16(qf1, k1b, s1);

    // t = tanh_poly(p), stored into per-wave LDS tile in D-layout
#pragma unroll
    for (int r = 0; r < 4; r++) {
      float t0 = tanh_poly(__expf(s0[r] - 8.f) * rz[r]);
      float t1 = tanh_poly(__expf(s1[r] - 8.f) * rz[r]);
      Tl[w][fg*4 + r][fr]      = f2bf(t0);
      Tl[w][fg*4 + r][16 + fr] = f2bf(t1);
    }
    // re-read in A-fragment layout (same wave; lgkmcnt ordering by compiler)
    bf16x8 af = *reinterpret_cast<const bf16x8*>(&Tl[w][fr][fg*8]);
#pragma unroll
    for (int e = 0; e < 4; e++) {
      bf16x8 bv = *reinterpret_cast<const bf16x8*>(&Vts[cur][e*16 + fr][fg*8]);
      o[e] = mfma16(af, bv, o[e]);
    }

    if (kt < 31) {
      *reinterpret_cast<int4*>(&Ks[cur ^ 1][krow][koff]) = kvn;
      *reinterpret_cast<int4*>(&Vts[cur ^ 1][vrow][voff]) = vvn;
    }
    __syncthreads();
    cur ^= 1;
  }

#pragma unroll
  for (int e = 0; e < 4; e++)
#pragma unroll
    for (int r = 0; r < 4; r++)
      outA[((size_t)(b * 1024 + qbase + fg*4 + r)) * 1024 + h * 64 + e*16 + fr] = o[e][r];
}

// ---------------------------------------------------------------------------
// Weights kernel: outW[b,q,k] = mean_h tanh(exp(s-8)*rcpZ).
// grid (qt=32, ks=2, b=8) = 512 blocks, 512 threads (8 waves).
// Wave w owns output frag (qi=w>>2, ki=w&3); K fragments read DIRECTLY from
// global (no LDS staging, no barriers in the loop). h outer / kt inner with
// wsum[8] register accumulators -> 8 independent chains for latency hiding.
// ---------------------------------------------------------------------------
__global__ __launch_bounds__(512) void attn_w_kernel(
    const u16* __restrict__ Qbf, const u16* __restrict__ Kbf,
    const float* __restrict__ rcpZ, float* __restrict__ outW)
{
  const int qt = blockIdx.x;
  const int ks = blockIdx.y;
  const int b  = blockIdx.z;
  const int tid  = threadIdx.x;
  const int lane = tid & 63;
  const int w    = tid >> 6;
  const int qi = w >> 2;   // 0..1
  const int ki = w & 3;    // 0..3
  const int fr = lane & 15;
  const int fg = lane >> 4;

  __shared__ u16 Qall[32][1032];     // 2064 B stride
  __shared__ float statsL[16][32];   // [h][row]

  {
    const int qrow = tid >> 4;            // 0..31
    const int qoffb = (tid & 15) * 64;
    const u16* qsrc = Qbf + ((size_t)(b * 1024 + qt * 32 + qrow)) * 1024 + qoffb;
#pragma unroll
    for (int i = 0; i < 8; i++)
      *reinterpret_cast<int4*>(&Qall[qrow][qoffb + i*8]) =
          *reinterpret_cast<const int4*>(qsrc + i*8);
    const int hh = tid >> 5, rr = tid & 31;
    statsL[hh][rr] = rcpZ[((size_t)(b * 16 + hh)) * 1024 + qt * 32 + rr];
  }
  __syncthreads();

  const u16* kbase = Kbf + ((size_t)(b * 1024 + ks * 512 + ki * 16 + fr)) * 1024 + fg * 8;

  f32x4 wsum[8];
#pragma unroll
  for (int kt = 0; kt < 8; kt++) wsum[kt] = f32x4{0.f, 0.f, 0.f, 0.f};

  for (int h = 0; h < 16; h++) {
    bf16x8 a0 = *reinterpret_cast<const bf16x8*>(&Qall[qi*16 + fr][h*64 + fg*8]);
    bf16x8 a1 = *reinterpret_cast<const bf16x8*>(&Qall[qi*16 + fr][h*64 + 32 + fg*8]);
    float rza[4];
#pragma unroll
    for (int r = 0; r < 4; r++) rza[r] = statsL[h][qi*16 + fg*4 + r];

#pragma unroll 4
    for (int kt = 0; kt < 8; kt++) {
      bf16x8 b0 = *reinterpret_cast<const bf16x8*>(kbase + (size_t)kt * 65536 + h * 64);
      bf16x8 b1 = *reinterpret_cast<const bf16x8*>(kbase + (size_t)kt * 65536 + h * 64 + 32);
      f32x4 s = {0.f, 0.f, 0.f, 0.f};
      s = mfma16(a0, b0, s);
      s = mfma16(a1, b1, s);
#pragma unroll
      for (int r = 0; r < 4; r++)
        wsum[kt][r] += tanh_poly(__expf(s[r] - 8.f) * rza[r]);
    }
  }

#pragma unroll
  for (int kt = 0; kt < 8; kt++)
#pragma unroll
    for (int r = 0; r < 4; r++)
      outW[((size_t)(b*1024 + qt*32 + qi*16 + fg*4 + r)) * 1024 + ks*512 + kt*64 + ki*16 + fr] =
          wsum[kt][r] * 0.0625f;
}

// ---------------------------------------------------------------------------
extern "C" void kernel_launch(void* const* d_in, const int* in_sizes, int n_in,
                              void* d_out, int out_size, void* d_ws, size_t ws_size,
                              hipStream_t stream) {
  const float* query = (const float*)d_in[0];
  const float* key_  = (const float*)d_in[1];
  const float* value = (const float*)d_in[2];
  const float* Wq = (const float*)d_in[3];
  const float* bq = (const float*)d_in[4];
  const float* Wk = (const float*)d_in[5];
  const float* bk = (const float*)d_in[6];
  const float* Wv = (const float*)d_in[7];
  const float* bv = (const float*)d_in[8];

  float* outA = (float*)d_out;            // [8,1024,1024]
  float* outW = outA + 8388608;           // [8,1024,1024]

  u16* Qbf = (u16*)d_ws;                  // bf16, Q pre-scaled by 1/8
  u16* Kbf = Qbf + 8388608;
  u16* Vt  = Kbf + 8388608;               // [B,H,64,S] transposed per head
  u16* Xbf = Vt + 8388608;                // 16.8MB reusable input slot
  u16* Wbf = Xbf + 8388608;               // 3 x 1M bf16 weights
  float* rcpZ = (float*)(Wbf + 3145728);  // [B,H,S]

  cvtW_kernel<<<dim3(512, 3), 256, 0, stream>>>(Wq, Wk, Wv, Wbf);

  cvt_kernel<<<4096, 256, 0, stream>>>(query, Xbf);
  proj_kernel<<<dim3(8, 64), 256, 0, stream>>>(Xbf, Wbf, bq, Qbf, 0, 0.125f);

  cvt_kernel<<<4096, 256, 0, stream>>>(key_, Xbf);
  proj_kernel<<<dim3(8, 64), 256, 0, stream>>>(Xbf, Wbf + 1048576, bk, Kbf, 1, 1.0f);

  cvt_kernel<<<4096, 256, 0, stream>>>(value, Xbf);
  proj_kernel<<<dim3(8, 64), 256, 0, stream>>>(Xbf, Wbf + 2097152, bv, Vt, 2, 1.0f);

  attn_out_kernel<<<dim3(2048), dim3(256), 0, stream>>>(Qbf, Kbf, Vt, outA, rcpZ);
  attn_w_kernel<<<dim3(32, 2, 8), 512, 0, stream>>>(Qbf, Kbf, rcpZ, outW);
}

// Round 7
// 351.919 us; speedup vs baseline: 1.6840x; 1.0284x over previous
//
#include <hip/hip_runtime.h>
#include <hip/hip_bf16.h>

using bf16x8 = __attribute__((ext_vector_type(8))) short;
using f32x4  = __attribute__((ext_vector_type(4))) float;
typedef unsigned short u16;

__device__ __forceinline__ u16 f2bf(float f) {
  unsigned int u = __float_as_uint(f);
  u += 0x7FFFu + ((u >> 16) & 1u);
  return (u16)(u >> 16);
}

__device__ __forceinline__ float bf2f(u16 b) {
  return __uint_as_float(((unsigned int)b) << 16);
}

__device__ __forceinline__ f32x4 mfma16(bf16x8 a, bf16x8 b, f32x4 c) {
  return __builtin_amdgcn_mfma_f32_16x16x32_bf16(a, b, c, 0, 0, 0);
}

// tanh(p) for softmax probs (p <= ~0.15 here): 3-term odd series,
// err = 17p^7/315 (<2e-7 at p=0.2, <3e-5 at p=0.4). 2 FMA + 2 mul.
__device__ __forceinline__ float tanh3(float p) {
  float x2 = p * p;
  return p * fmaf(x2, fmaf(x2, 0.13333333f, -0.33333333f), 1.0f);
}

#define GLL16(gp, lp) __builtin_amdgcn_global_load_lds( \
    (const __attribute__((address_space(1))) unsigned*)(gp), \
    (__attribute__((address_space(3))) unsigned*)(lp), 16, 0, 0)

// ---------------------------------------------------------------------------
// fp32 -> bf16 converts (memory-bound). cvtX: z picks q/k/v input.
// ---------------------------------------------------------------------------
__global__ __launch_bounds__(256) void cvtX_kernel(
    const float* __restrict__ x0, const float* __restrict__ x1,
    const float* __restrict__ x2, u16* __restrict__ d0,
    u16* __restrict__ d1, u16* __restrict__ d2) {
  const float* src = (blockIdx.y == 0) ? x0 : (blockIdx.y == 1) ? x1 : x2;
  u16* dst = (blockIdx.y == 0) ? d0 : (blockIdx.y == 1) ? d1 : d2;
  const int i = (blockIdx.x * 256 + threadIdx.x) * 8;
  float4 v0 = *reinterpret_cast<const float4*>(src + i);
  float4 v1 = *reinterpret_cast<const float4*>(src + i + 4);
  u16 o[8] = {f2bf(v0.x), f2bf(v0.y), f2bf(v0.z), f2bf(v0.w),
              f2bf(v1.x), f2bf(v1.y), f2bf(v1.z), f2bf(v1.w)};
  *reinterpret_cast<int4*>(dst + i) = *reinterpret_cast<int4*>(o);
}

__global__ __launch_bounds__(256) void cvtW_kernel(
    const float* __restrict__ w0, const float* __restrict__ w1,
    const float* __restrict__ w2, u16* __restrict__ dst) {
  const float* src = (blockIdx.y == 0) ? w0 : (blockIdx.y == 1) ? w1 : w2;
  u16* d = dst + (size_t)blockIdx.y * 1048576;
  const int i = (blockIdx.x * 256 + threadIdx.x) * 8;
  float4 v0 = *reinterpret_cast<const float4*>(src + i);
  float4 v1 = *reinterpret_cast<const float4*>(src + i + 4);
  u16 o[8] = {f2bf(v0.x), f2bf(v0.y), f2bf(v0.z), f2bf(v0.w),
              f2bf(v1.x), f2bf(v1.y), f2bf(v1.z), f2bf(v1.w)};
  *reinterpret_cast<int4*>(d + i) = *reinterpret_cast<int4*>(o);
}

// ---------------------------------------------------------------------------
// Projection GEMM (bf16 in/out), all three mats in one launch (grid.z).
// m97 structure: global_load_lds width-16 staging into LINEAR [128][32] LDS,
// double-buffered, one barrier per K-step, prefetch next tile before compute.
// mat 0: Q*0.125 (normal layout), 1: K (normal), 2: V (transposed per head:
//        Y[(b*1024 + n)*1024 + s])
// ---------------------------------------------------------------------------
__global__ __launch_bounds__(256) void proj_kernel(
    const u16* __restrict__ Xq, const u16* __restrict__ Xk,
    const u16* __restrict__ Xv, const u16* __restrict__ Wbf,
    const float* __restrict__ Bq, const float* __restrict__ Bk,
    const float* __restrict__ Bv,
    u16* __restrict__ Yq, u16* __restrict__ Yk, u16* __restrict__ Yv)
{
  const int mat = blockIdx.z;
  const u16* X  = (mat == 0) ? Xq : (mat == 1) ? Xk : Xv;
  const u16* W  = Wbf + (size_t)mat * 1048576;
  const float* Bi = (mat == 0) ? Bq : (mat == 1) ? Bk : Bv;
  u16* Y = (mat == 0) ? Yq : (mat == 1) ? Yk : Yv;
  const float scale = (mat == 0) ? 0.125f : 1.0f;

  __shared__ u16 As[2][128][32];   // 8 KB per buffer, linear (gll requirement)
  __shared__ u16 Bs[2][128][32];

  const int tid  = threadIdx.x;
  const int lane = tid & 63;
  const int w    = tid >> 6;
  const int m0 = blockIdx.y * 128;
  const int n0 = blockIdx.x * 128;
  const int wm = (w >> 1) * 64;
  const int wn = (w & 1) * 64;
  const int fr = lane & 15;
  const int fg = lane >> 4;

  const int srow = lane >> 2;
  const int scol = (lane & 3) * 8;
  const u16* agp = X + (size_t)(m0 + w*32 + srow) * 1024 + scol;
  const u16* bgp = W + (size_t)(n0 + w*32 + srow) * 1024 + scol;

  f32x4 zero = {0.f, 0.f, 0.f, 0.f};
  f32x4 acc[4][4];
#pragma unroll
  for (int i = 0; i < 4; i++)
#pragma unroll
    for (int j = 0; j < 4; j++) acc[i][j] = zero;

#define STAGE(buf, kk)                                            \
  do {                                                            \
    GLL16(agp + (kk),            &As[buf][w*32     ][0]);         \
    GLL16(agp + (kk) + 16*1024,  &As[buf][w*32 + 16][0]);         \
    GLL16(bgp + (kk),            &Bs[buf][w*32     ][0]);         \
    GLL16(bgp + (kk) + 16*1024,  &Bs[buf][w*32 + 16][0]);         \
  } while (0)

  STAGE(0, 0);
  __syncthreads();   // drains vmcnt (gll) + barrier

  int cur = 0;
  for (int kt = 0; kt < 32; kt++) {
    if (kt < 31) STAGE(cur ^ 1, (kt + 1) * 32);

    bf16x8 af[4], bff[4];
#pragma unroll
    for (int i = 0; i < 4; i++) {
      af[i]  = *reinterpret_cast<const bf16x8*>(&As[cur][wm + i*16 + fr][fg*8]);
      bff[i] = *reinterpret_cast<const bf16x8*>(&Bs[cur][wn + i*16 + fr][fg*8]);
    }
#pragma unroll
    for (int i = 0; i < 4; i++)
#pragma unroll
      for (int j = 0; j < 4; j++)
        acc[i][j] = mfma16(af[i], bff[j], acc[i][j]);

    __syncthreads();  // drains prefetch vmcnt + lgkm; flip buffers
    cur ^= 1;
  }
#undef STAGE

  // epilogue: C/D layout row=(lane>>4)*4+reg, col=lane&15
#pragma unroll
  for (int j = 0; j < 4; j++) {
    const int n = n0 + wn + j*16 + fr;
    const float bias = Bi[n];
#pragma unroll
    for (int i = 0; i < 4; i++) {
      const int mbase = m0 + wm + i*16 + fg*4;
      if (mat == 2) {
        u16 pk[4];
#pragma unroll
        for (int r = 0; r < 4; r++) pk[r] = f2bf((acc[i][j][r] + bias) * scale);
        const int bidx = mbase >> 10;
        const int s = mbase & 1023;
        *reinterpret_cast<uint2*>(&Y[((size_t)(bidx * 1024 + n)) * 1024 + s]) =
            *reinterpret_cast<uint2*>(pk);
      } else {
#pragma unroll
        for (int r = 0; r < 4; r++) {
          Y[(size_t)(mbase + r) * 1024 + n] = f2bf((acc[i][j][r] + bias) * scale);
        }
      }
    }
  }
}

// ---------------------------------------------------------------------------
// Attention output kernel. 2048 blocks, 256 threads (4 waves).
// XCD-locality decode (R4-proven: FETCH 218->25MB): all 16 q-tile blocks of
// a (b,h) share an XCD so its 256KB K/V slice stays L2-resident.
// LDS-staged K/V + async-split double buffering: ONE barrier per kt.
// Wave w handles q rows [qt*64 + w*16, +16).
// Pass 1: Z = sum_k exp(s-8).  Pass 2: t = tanh3(exp(s+ln(rz)-8)), O += t@V.
// ---------------------------------------------------------------------------
__global__ __launch_bounds__(256) void attn_out_kernel(
    const u16* __restrict__ Qbf, const u16* __restrict__ Kbf, const u16* __restrict__ Vt,
    float* __restrict__ outA, float* __restrict__ rcpZ)
{
  const int bid = blockIdx.x;
  const int xcd = bid & 7;
  const int wi  = bid >> 3;
  const int qt  = wi & 15;
  const int bh  = ((wi >> 4) << 3) | xcd;  // bijective; same (b,h) -> same XCD
  const int b   = bh >> 4;
  const int h   = bh & 15;

  const int tid  = threadIdx.x;
  const int lane = tid & 63;
  const int w    = tid >> 6;
  const int fr = lane & 15;
  const int fg = lane >> 4;

  __shared__ u16 Ks[2][32][88];   // 11264 B, 176B stride (2-way bank max)
  __shared__ u16 Vts[2][64][40];  // 10240 B, [e][k] (V pre-transposed in ws)
  __shared__ u16 Tl[4][16][40];   // 5120 B per-wave t relayout buffer

  const int qbase = qt * 64 + w * 16;

  // Q fragments (Q pre-scaled by 1/8 at projection time)
  const u16* qp = Qbf + ((size_t)(b * 1024 + qbase + fr)) * 1024 + h * 64 + fg * 8;
  const bf16x8 qf0 = *reinterpret_cast<const bf16x8*>(qp);
  const bf16x8 qf1 = *reinterpret_cast<const bf16x8*>(qp + 32);

  const int krow = tid >> 3;            // 0..31
  const int koff = (tid & 7) * 8;       // 0..56
  const u16* kp = Kbf + ((size_t)(b * 1024 + krow)) * 1024 + h * 64 + koff;

  const int vrow = tid >> 2;            // 0..63 (e)
  const int voff = (tid & 3) * 8;       // 0..24 (k within tile)
  const u16* vp = Vt + ((size_t)((b * 16 + h) * 64 + vrow)) * 1024 + voff;

  f32x4 zero = {0.f, 0.f, 0.f, 0.f};
  float zacc[4] = {0.f, 0.f, 0.f, 0.f};

  // ---------------- pass 1: Z ----------------
  {
    int4 kv = *reinterpret_cast<const int4*>(kp);
    *reinterpret_cast<int4*>(&Ks[0][krow][koff]) = kv;
  }
  __syncthreads();
  int cur = 0;
  for (int kt = 0; kt < 32; kt++) {
    int4 kvn;
    if (kt < 31) kvn = *reinterpret_cast<const int4*>(kp + (size_t)(kt + 1) * 32 * 1024);

    bf16x8 k0a = *reinterpret_cast<const bf16x8*>(&Ks[cur][fr][fg*8]);
    bf16x8 k0b = *reinterpret_cast<const bf16x8*>(&Ks[cur][fr][32 + fg*8]);
    bf16x8 k1a = *reinterpret_cast<const bf16x8*>(&Ks[cur][16 + fr][fg*8]);
    bf16x8 k1b = *reinterpret_cast<const bf16x8*>(&Ks[cur][16 + fr][32 + fg*8]);
    f32x4 s0 = zero, s1 = zero;
    s0 = mfma16(qf0, k0a, s0); s0 = mfma16(qf1, k0b, s0);
    s1 = mfma16(qf0, k1a, s1); s1 = mfma16(qf1, k1b, s1);
#pragma unroll
    for (int r = 0; r < 4; r++)
      zacc[r] += __expf(s0[r] - 8.f) + __expf(s1[r] - 8.f);

    if (kt < 31) *reinterpret_cast<int4*>(&Ks[cur ^ 1][krow][koff]) = kvn;
    __syncthreads();
    cur ^= 1;
  }
#pragma unroll
  for (int r = 0; r < 4; r++) {
    float z = zacc[r];
    z += __shfl_xor(z, 1); z += __shfl_xor(z, 2);
    z += __shfl_xor(z, 4); z += __shfl_xor(z, 8);
    zacc[r] = z;
  }
  float rz[4], cl[4];
#pragma unroll
  for (int r = 0; r < 4; r++) {
    rz[r] = 1.0f / zacc[r];
    cl[r] = __logf(rz[r]) - 8.f;   // fold 1/Z and the -8 shift into exp arg
  }
  if (fr == 0) {
#pragma unroll
    for (int r = 0; r < 4; r++)
      rcpZ[((size_t)(b * 16 + h)) * 1024 + qbase + fg * 4 + r] = rz[r];
  }

  // ---------------- pass 2: O = tanh(p) @ V ----------------
  f32x4 o[4];
#pragma unroll
  for (int e = 0; e < 4; e++) o[e] = zero;

  {
    int4 kv = *reinterpret_cast<const int4*>(kp);
    int4 vv = *reinterpret_cast<const int4*>(vp);
    *reinterpret_cast<int4*>(&Ks[0][krow][koff]) = kv;
    *reinterpret_cast<int4*>(&Vts[0][vrow][voff]) = vv;
  }
  __syncthreads();
  cur = 0;
  for (int kt = 0; kt < 32; kt++) {
    int4 kvn, vvn;
    if (kt < 31) {
      kvn = *reinterpret_cast<const int4*>(kp + (size_t)(kt + 1) * 32 * 1024);
      vvn = *reinterpret_cast<const int4*>(vp + (kt + 1) * 32);
    }

    bf16x8 k0a = *reinterpret_cast<const bf16x8*>(&Ks[cur][fr][fg*8]);
    bf16x8 k0b = *reinterpret_cast<const bf16x8*>(&Ks[cur][fr][32 + fg*8]);
    bf16x8 k1a = *reinterpret_cast<const bf16x8*>(&Ks[cur][16 + fr][fg*8]);
    bf16x8 k1b = *reinterpret_cast<const bf16x8*>(&Ks[cur][16 + fr][32 + fg*8]);
    f32x4 s0 = zero, s1 = zero;
    s0 = mfma16(qf0, k0a, s0); s0 = mfma16(qf1, k0b, s0);
    s1 = mfma16(qf0, k1a, s1); s1 = mfma16(qf1, k1b, s1);

    // t = tanh3(exp(s + cl)), stored into per-wave LDS tile in D-layout
#pragma unroll
    for (int r = 0; r < 4; r++) {
      float t0 = tanh3(__expf(s0[r] + cl[r]));
      float t1 = tanh3(__expf(s1[r] + cl[r]));
      Tl[w][fg*4 + r][fr]      = f2bf(t0);
      Tl[w][fg*4 + r][16 + fr] = f2bf(t1);
    }
    // re-read in A-fragment layout (same wave; lgkmcnt ordering by compiler)
    bf16x8 af = *reinterpret_cast<const bf16x8*>(&Tl[w][fr][fg*8]);
#pragma unroll
    for (int e = 0; e < 4; e++) {
      bf16x8 bv = *reinterpret_cast<const bf16x8*>(&Vts[cur][e*16 + fr][fg*8]);
      o[e] = mfma16(af, bv, o[e]);
    }

    if (kt < 31) {
      *reinterpret_cast<int4*>(&Ks[cur ^ 1][krow][koff]) = kvn;
      *reinterpret_cast<int4*>(&Vts[cur ^ 1][vrow][voff]) = vvn;
    }
    __syncthreads();
    cur ^= 1;
  }

#pragma unroll
  for (int e = 0; e < 4; e++)
#pragma unroll
    for (int r = 0; r < 4; r++)
      outA[((size_t)(b * 1024 + qbase + fg*4 + r)) * 1024 + h * 64 + e*16 + fr] = o[e][r];
}

// ---------------------------------------------------------------------------
// Weights kernel: outW[b,q,k] = mean_h tanh(exp(s + ln(rz) - 8)).
// grid (qt=32, ks=2, b=8) = 512 blocks, 512 threads (8 waves).
// NO per-block LDS tiles: Q and K fragments read directly from global (both
// L2-resident; Q 64KB tile reused 16x, K slice shared by 32 qt-blocks).
// LDS = 2KB stats only -> 4 blocks/CU occupancy. Zero barriers in the loop.
// wsum[8] register accumulators give 8 independent chains per wave.
// ---------------------------------------------------------------------------
__global__ __launch_bounds__(512) void attn_w_kernel(
    const u16* __restrict__ Qbf, const u16* __restrict__ Kbf,
    const float* __restrict__ rcpZ, float* __restrict__ outW)
{
  const int qt = blockIdx.x;
  const int ks = blockIdx.y;
  const int b  = blockIdx.z;
  const int tid  = threadIdx.x;
  const int lane = tid & 63;
  const int w    = tid >> 6;
  const int qi = w >> 2;   // 0..1
  const int ki = w & 3;    // 0..3
  const int fr = lane & 15;
  const int fg = lane >> 4;

  __shared__ float statsL[16][32];   // [h][row]: ln(rz) - 8

  {
    const int hh = tid >> 5, rr = tid & 31;
    float rzv = rcpZ[((size_t)(b * 16 + hh)) * 1024 + qt * 32 + rr];
    statsL[hh][rr] = __logf(rzv) - 8.f;
  }
  __syncthreads();

  // Q A-frag base: row qt*32 + qi*16 + fr, col h*64 + fg*8 (+32)
  const u16* qp = Qbf + ((size_t)(b * 1024 + qt * 32 + qi * 16 + fr)) * 1024 + fg * 8;
  const u16* kbase = Kbf + ((size_t)(b * 1024 + ks * 512 + ki * 16 + fr)) * 1024 + fg * 8;

  f32x4 wsum[8];
#pragma unroll
  for (int kt = 0; kt < 8; kt++) wsum[kt] = f32x4{0.f, 0.f, 0.f, 0.f};

  for (int h = 0; h < 16; h++) {
    bf16x8 a0 = *reinterpret_cast<const bf16x8*>(qp + h * 64);
    bf16x8 a1 = *reinterpret_cast<const bf16x8*>(qp + h * 64 + 32);
    float cl[4];
#pragma unroll
    for (int r = 0; r < 4; r++) cl[r] = statsL[h][qi*16 + fg*4 + r];

#pragma unroll 4
    for (int kt = 0; kt < 8; kt++) {
      bf16x8 b0 = *reinterpret_cast<const bf16x8*>(kbase + (size_t)kt * 65536 + h * 64);
      bf16x8 b1 = *reinterpret_cast<const bf16x8*>(kbase + (size_t)kt * 65536 + h * 64 + 32);
      f32x4 s = {0.f, 0.f, 0.f, 0.f};
      s = mfma16(a0, b0, s);
      s = mfma16(a1, b1, s);
#pragma unroll
      for (int r = 0; r < 4; r++)
        wsum[kt][r] += tanh3(__expf(s[r] + cl[r]));
    }
  }

#pragma unroll
  for (int kt = 0; kt < 8; kt++)
#pragma unroll
    for (int r = 0; r < 4; r++)
      outW[((size_t)(b*1024 + qt*32 + qi*16 + fg*4 + r)) * 1024 + ks*512 + kt*64 + ki*16 + fr] =
          wsum[kt][r] * 0.0625f;
}

// ---------------------------------------------------------------------------
extern "C" void kernel_launch(void* const* d_in, const int* in_sizes, int n_in,
                              void* d_out, int out_size, void* d_ws, size_t ws_size,
                              hipStream_t stream) {
  const float* query = (const float*)d_in[0];
  const float* key_  = (const float*)d_in[1];
  const float* value = (const float*)d_in[2];
  const float* Wq = (const float*)d_in[3];
  const float* bq = (const float*)d_in[4];
  const float* Wk = (const float*)d_in[5];
  const float* bk = (const float*)d_in[6];
  const float* Wv = (const float*)d_in[7];
  const float* bv = (const float*)d_in[8];

  float* outA = (float*)d_out;            // [8,1024,1024]
  float* outW = outA + 8388608;           // [8,1024,1024]

  u16* Qbf = (u16*)d_ws;                  // bf16, Q pre-scaled by 1/8
  u16* Kbf = Qbf + 8388608;
  u16* Vt  = Kbf + 8388608;               // [B,H,64,S] transposed per head
  u16* Xq  = Vt + 8388608;                // 3 x 16.8MB bf16 input slots
  u16* Xk  = Xq + 8388608;
  u16* Xv  = Xk + 8388608;
  u16* Wbf = Xv + 8388608;                // 3 x 1M bf16 weights
  float* rcpZ = (float*)(Wbf + 3145728);  // [B,H,S]

  cvtW_kernel<<<dim3(512, 3), 256, 0, stream>>>(Wq, Wk, Wv, Wbf);
  cvtX_kernel<<<dim3(4096, 3), 256, 0, stream>>>(query, key_, value, Xq, Xk, Xv);
  proj_kernel<<<dim3(8, 64, 3), 256, 0, stream>>>(
      Xq, Xk, Xv, Wbf, bq, bk, bv, Qbf, Kbf, Vt);
  attn_out_kernel<<<dim3(2048), dim3(256), 0, stream>>>(Qbf, Kbf, Vt, outA, rcpZ);
  attn_w_kernel<<<dim3(32, 2, 8), 512, 0, stream>>>(Qbf, Kbf, rcpZ, outW);
}